// Round 4
// baseline (2135.208 us; speedup 1.0000x reference)
//
#include <hip/hip_runtime.h>
#include <hip/hip_fp16.h>

// LightGCN 3-layer propagation, fp16 ego intermediates.
// Round 10: the LDS-accumulate gather was 8x slow because atomicAdd on
// __shared__ float compiles to a CAS retry loop under plain -O3 (no
// -munsafe-fp-atomics): VALU 3%, HBM 3%, everything stalled on
// ds_cmpst_rtn round trips. Fix: unsafeAtomicAdd -> hardware ds_add_f32
// (fire-and-forget, no return, no retry). Also permute the per-row dim
// layout (lane l's dims 2l,2l+1 stored at offsets l, l+32; stride 65) so
// each ds_add_f32 instruction hits all 32 banks exactly 2-way (free).

#define NUM_USERS 100000
#define NUM_ITEMS 50000
#define EMB_DIM   64
#define N_EDGES   2000000
#define N_NODES   (NUM_USERS + NUM_ITEMS)          // 150000
#define NODE_FLOATS (N_NODES * EMB_DIM)            // 9,600,000
#define NODE_F4     (NODE_FLOATS / 4)              // 2,400,000

#define NBUCKET  512
#define NPB      293        // nodes per bucket; 512*293 = 150016 >= 150000
#define NPART    8          // reservation partitions (XCD heuristic)
#define NCNT     (NBUCKET * NPART)                  // 4096
#define BT       512        // threads in bucket passes
#define VPT      8          // edges per thread in bucket passes
#define TILE     (BT * VPT)                         // 4096
#define NTILE    ((N_EDGES + TILE - 1) / TILE)      // 489

#define GT       1024       // gather threads (32 half-wave streams)
#define ACC_LD   65         // padded LDS row stride (odd -> bank spread)

typedef unsigned int uint;
typedef unsigned short ushort;
typedef unsigned long long u64;
typedef __attribute__((ext_vector_type(2))) float fv2;

__device__ __forceinline__ float2 h2f2(uint u) {
    __half2 h = *reinterpret_cast<const __half2*>(&u);
    return __half22float2(h);
}
__device__ __forceinline__ uint f2h2(float a, float b) {
    __half2 h = __floats2half2_rn(a, b);
    return *reinterpret_cast<uint*>(&h);
}

// ---------- init: egoA(fp16) = concat(user,item) ----------
__global__ void lgcn_init(const float4* __restrict__ user,
                          const float4* __restrict__ item,
                          uint2* __restrict__ egoA) {
    const int n_user4 = NUM_USERS * EMB_DIM / 4;
    for (int i = blockIdx.x * blockDim.x + threadIdx.x; i < NODE_F4;
         i += gridDim.x * blockDim.x) {
        float4 v = (i < n_user4) ? user[i] : item[i - n_user4];
        egoA[i] = make_uint2(f2h2(v.x, v.y), f2h2(v.z, v.w));
    }
}

__global__ void zero_ints(int* __restrict__ p, int n) {
    int i = blockIdx.x * blockDim.x + threadIdx.x;
    if (i < n) p[i] = 0;
}

// ---------- pass A: histogram into (bucket, partition) counters ----------
__global__ __launch_bounds__(BT) void bucket_hist(const int* __restrict__ src,
                                                  int* __restrict__ bucketCount) {
    __shared__ int cnt[NBUCKET];
    int t = threadIdx.x;
    int part = blockIdx.x & (NPART - 1);
    cnt[t] = 0;
    __syncthreads();
    int base = blockIdx.x * TILE + t;
    #pragma unroll
    for (int k = 0; k < VPT; ++k) {
        int e = base + k * BT;
        if (e < N_EDGES) atomicAdd(&cnt[src[e] / NPB], 1);
    }
    __syncthreads();
    int c = cnt[t];
    if (c) atomicAdd(&bucketCount[t * NPART + part], c);
}

// ---------- scan over 4096 (bucket,part) counters (1 block, 1024 thr) ----------
__global__ __launch_bounds__(1024) void bucket_scan(const int* __restrict__ bucketCount,
                                                    int* __restrict__ bucketOffset,
                                                    int* __restrict__ gCur) {
    __shared__ int s[1024];
    int t = threadIdx.x;
    int4 c = *(const int4*)(bucketCount + t * 4);
    int sum = c.x + c.y + c.z + c.w;
    s[t] = sum;
    __syncthreads();
    for (int off = 1; off < 1024; off <<= 1) {
        int x = (t >= off) ? s[t - off] : 0;
        __syncthreads();
        s[t] += x;
        __syncthreads();
    }
    int base = s[t] - sum;   // exclusive
    int i0 = t * 4;
    bucketOffset[i0]     = base;
    bucketOffset[i0 + 1] = base + c.x;
    bucketOffset[i0 + 2] = base + c.x + c.y;
    bucketOffset[i0 + 3] = base + c.x + c.y + c.z;
    gCur[i0]     = base;
    gCur[i0 + 1] = base + c.x;
    gCur[i0 + 2] = base + c.x + c.y;
    gCur[i0 + 3] = base + c.x + c.y + c.z;
    if (t == 0) bucketOffset[NCNT] = N_EDGES;
}

// ---------- pass B: scatter packed edges into (bucket,part) runs ----------
// packed u64: [norm:32][src_local:9][dst:18]
__global__ __launch_bounds__(BT) void bucket_scatter(const int* __restrict__ src,
                                                     const int* __restrict__ dst,
                                                     const float* __restrict__ norm,
                                                     int* __restrict__ gCur,
                                                     u64* __restrict__ bpair) {
    __shared__ int cnt[NBUCKET];
    __shared__ int bbase[NBUCKET];
    int t = threadIdx.x;
    int part = blockIdx.x & (NPART - 1);
    cnt[t] = 0;
    __syncthreads();
    int base = blockIdx.x * TILE + t;
    #pragma unroll
    for (int k = 0; k < VPT; ++k) {
        int e = base + k * BT;
        if (e < N_EDGES) atomicAdd(&cnt[src[e] / NPB], 1);
    }
    __syncthreads();
    int c = cnt[t];
    bbase[t] = c ? atomicAdd(&gCur[t * NPART + part], c) : 0;
    __syncthreads();
    cnt[t] = 0;
    __syncthreads();
    #pragma unroll
    for (int k = 0; k < VPT; ++k) {
        int e = base + k * BT;
        if (e < N_EDGES) {
            int s = src[e];
            int b = s / NPB;
            int sl = s - b * NPB;                    // 0..292
            int r = atomicAdd(&cnt[b], 1);
            uint lo = (uint)dst[e] | ((uint)sl << 18);
            u64 packed = (u64)lo | ((u64)(uint)__float_as_uint(norm[e]) << 32);
            bpair[bbase[b] + r] = packed;
        }
    }
}

// ---------- gather: 1 bucket/block, fp32 LDS accumulators, unsorted edges ----
// LDS row layout is PERMUTED: lane l's dims (2l, 2l+1) live at row offsets
// l and l+32, so each ds_add_f32 wave-instruction spreads over all 32
// banks (2 rows x 32 lanes = exact 2-way, free).
// finalMode==0: nego = fp16(s)
// finalMode==1: acc  = (e0 + e1 + ego + s) * 0.25
__global__ __launch_bounds__(GT) void lgcn_gather_lds(
        const ushort* __restrict__ ego,
        ushort* __restrict__ nego,
        float* __restrict__ acc,
        const ushort* __restrict__ e0,
        const ushort* __restrict__ e1,
        const int* __restrict__ bucketOffset,
        const u64* __restrict__ bpair,
        int finalMode) {
    __shared__ float accs[NPB * ACC_LD];              // 76,180 B (2 blocks/CU)
    int b = blockIdx.x;
    int t = threadIdx.x;
    int beg = bucketOffset[b * NPART];
    int end = bucketOffset[(b + 1) * NPART];

    for (int i = t; i < NPB * ACC_LD; i += GT) accs[i] = 0.f;
    __syncthreads();

    int hw = t >> 5;            // 32 half-wave edge streams
    int l  = t & 31;            // lane within half-wave: dims 2l, 2l+1
    for (int i = beg + hw; i < end; i += 64) {
        int i2 = i + 32;
        u64 pA = __builtin_nontemporal_load(&bpair[i]);
        u64 pB = (i2 < end) ? __builtin_nontemporal_load(&bpair[i2])
                            : (u64)0;                 // w=0 -> harmless add
        uint loA = (uint)pA, loB = (uint)pB;
        float wA = __uint_as_float((uint)(pA >> 32));
        float wB = __uint_as_float((uint)(pB >> 32));
        uint rA = *(const uint*)(ego + ((size_t)(loA & 0x3FFFF) << 6) + (l << 1));
        uint rB = *(const uint*)(ego + ((size_t)(loB & 0x3FFFF) << 6) + (l << 1));
        int slA = (loA >> 18) & 0x1FF;
        int slB = (loB >> 18) & 0x1FF;
        float2 qA = h2f2(rA);
        float2 qB = h2f2(rB);
        unsafeAtomicAdd(&accs[slA * ACC_LD + l],      wA * qA.x);   // dim 2l
        unsafeAtomicAdd(&accs[slA * ACC_LD + l + 32], wA * qA.y);   // dim 2l+1
        unsafeAtomicAdd(&accs[slB * ACC_LD + l],      wB * qB.x);
        unsafeAtomicAdd(&accs[slB * ACC_LD + l + 32], wB * qB.y);
    }
    __syncthreads();

    int nodeBase = b * NPB;
    int nrows = N_NODES - nodeBase;
    if (nrows > NPB) nrows = NPB;

    if (!finalMode) {
        uint* np = (uint*)nego;
        for (int idx = t; idx < nrows * 32; idx += GT) {
            int row = idx >> 5, dp = idx & 31;       // dims 2dp, 2dp+1
            float x = accs[row * ACC_LD + dp];
            float y = accs[row * ACC_LD + dp + 32];
            np[((size_t)(nodeBase + row) << 5) + dp] = f2h2(x, y);
        }
    } else {
        const uint* p0 = (const uint*)e0;
        const uint* p1 = (const uint*)e1;
        const uint* p2 = (const uint*)ego;
        fv2* ap = (fv2*)acc;
        for (int idx = t; idx < nrows * 32; idx += GT) {
            int row = idx >> 5, dp = idx & 31;
            size_t o = ((size_t)(nodeBase + row) << 5) + dp;
            float sx = accs[row * ACC_LD + dp];
            float sy = accs[row * ACC_LD + dp + 32];
            float2 a = h2f2(__builtin_nontemporal_load(&p0[o]));
            float2 bb = h2f2(__builtin_nontemporal_load(&p1[o]));
            float2 c = h2f2(__builtin_nontemporal_load(&p2[o]));
            fv2 ov;
            ov.x = (a.x + bb.x + c.x + sx) * 0.25f;
            ov.y = (a.y + bb.y + c.y + sy) * 0.25f;
            __builtin_nontemporal_store(ov, &ap[o]);
        }
    }
}

extern "C" void kernel_launch(void* const* d_in, const int* in_sizes, int n_in,
                              void* d_out, int out_size, void* d_ws, size_t ws_size,
                              hipStream_t stream) {
    const float* user_emb  = (const float*)d_in[0];
    const float* item_emb  = (const float*)d_in[1];
    const float* edge_norm = (const float*)d_in[2];
    const int*   edge_src  = (const int*)d_in[3];
    const int*   edge_dst  = (const int*)d_in[4];
    float* acc = (float*)d_out;

    char* w = (char*)d_ws;
    ushort* egoA  = (ushort*)w;                      w += (size_t)NODE_FLOATS * 2;   // 19.2 MB
    ushort* egoB  = (ushort*)w;                      w += (size_t)NODE_FLOATS * 2;   // 19.2 MB
    ushort* egoC  = (ushort*)w;                      w += (size_t)NODE_FLOATS * 2;   // 19.2 MB
    u64*   bpair  = (u64*)w;                         w += (size_t)N_EDGES * 8;       // 16 MB
    int*   bucketCount  = (int*)w;                   w += (size_t)NCNT * 4;
    int*   bucketOffset = (int*)w;                   w += (size_t)(NCNT + 4) * 4;
    int*   gCur   = (int*)w;

    const int T = 256;
    const int EW_BLOCKS = 2048;

    lgcn_init<<<EW_BLOCKS, T, 0, stream>>>(
        (const float4*)user_emb, (const float4*)item_emb, (uint2*)egoA);

    zero_ints<<<NCNT / T, T, 0, stream>>>(bucketCount, NCNT);
    bucket_hist<<<NTILE, BT, 0, stream>>>(edge_src, bucketCount);
    bucket_scan<<<1, 1024, 0, stream>>>(bucketCount, bucketOffset, gCur);
    bucket_scatter<<<NTILE, BT, 0, stream>>>(edge_src, edge_dst, edge_norm,
                                             gCur, bpair);

    // Layer 1: ego0(A) -> ego1(B)
    lgcn_gather_lds<<<NBUCKET, GT, 0, stream>>>(egoA, egoB, acc,
                                                (const ushort*)0, (const ushort*)0,
                                                bucketOffset, bpair, 0);
    // Layer 2: ego1(B) -> ego2(C)
    lgcn_gather_lds<<<NBUCKET, GT, 0, stream>>>(egoB, egoC, acc,
                                                (const ushort*)0, (const ushort*)0,
                                                bucketOffset, bpair, 0);
    // Layer 3: ego2(C) -> s; acc = (A + B + C + s) / 4
    lgcn_gather_lds<<<NBUCKET, GT, 0, stream>>>(egoC, (ushort*)0, acc,
                                                egoA, egoB,
                                                bucketOffset, bpair, 1);
}

// Round 5
// 345.530 us; speedup vs baseline: 6.1795x; 6.1795x over previous
//
#include <hip/hip_runtime.h>
#include <hip/hip_fp16.h>

// LightGCN 3-layer propagation, pull-based CSR, fp16 ego intermediates.
// Round 11: REVERT to the round-8 structure (392.6 us verified; the LDS-
// accumulate experiment was 8x slower at identical counters across three
// variants -> falsified, latency-bound with only 8192 waves of MLP).
// Gather changes vs round 8:
//  (1) 2 nodes/wave: 4 edge-streams x 8 lanes per node (was 8 streams).
//      deg~13 -> ~3.3 loop iters/stream (pipelinable), 16 shuffles not 24,
//      half the per-node tail overhead, 75K waves each 2x useful work.
//  (2) pairs loads are NOT nontemporal anymore: read 3x (per layer), and
//      per-XCD slice ~2MB < 4MB L2 with identical block->XCD mapping
//      across the 3 launches -> layers 2/3 pairs reads can L2-hit.

#define NUM_USERS 100000
#define NUM_ITEMS 50000
#define EMB_DIM   64
#define N_EDGES   2000000
#define N_NODES   (NUM_USERS + NUM_ITEMS)          // 150000
#define NODE_FLOATS (N_NODES * EMB_DIM)            // 9,600,000
#define NODE_F4     (NODE_FLOATS / 4)              // 2,400,000

#define NBUCKET  512
#define NPB      293        // nodes per bucket; 512*293 = 150016 >= 150000
#define NPART    8          // reservation partitions (XCD heuristic)
#define NCNT     (NBUCKET * NPART)                  // 4096
#define BT       512        // threads in bucket passes
#define VPT      8          // edges per thread in bucket passes
#define TILE     (BT * VPT)                         // 4096
#define NTILE    ((N_EDGES + TILE - 1) / TILE)      // 489

typedef unsigned int uint;
typedef unsigned short ushort;
typedef unsigned long long u64;

__device__ __forceinline__ float2 h2f2(uint u) {
    __half2 h = *reinterpret_cast<const __half2*>(&u);
    return __half22float2(h);
}
__device__ __forceinline__ uint f2h2(float a, float b) {
    __half2 h = __floats2half2_rn(a, b);
    return *reinterpret_cast<uint*>(&h);
}

// ---------- init: egoA(fp16) = concat(user,item) ----------
__global__ void lgcn_init(const float4* __restrict__ user,
                          const float4* __restrict__ item,
                          uint2* __restrict__ egoA) {
    const int n_user4 = NUM_USERS * EMB_DIM / 4;
    for (int i = blockIdx.x * blockDim.x + threadIdx.x; i < NODE_F4;
         i += gridDim.x * blockDim.x) {
        float4 v = (i < n_user4) ? user[i] : item[i - n_user4];
        egoA[i] = make_uint2(f2h2(v.x, v.y), f2h2(v.z, v.w));
    }
}

__global__ void zero_ints(int* __restrict__ p, int n) {
    int i = blockIdx.x * blockDim.x + threadIdx.x;
    if (i < n) p[i] = 0;
}

// ---------- pass A: histogram into (bucket, partition) counters ----------
__global__ __launch_bounds__(BT) void bucket_hist(const int* __restrict__ src,
                                                  int* __restrict__ bucketCount) {
    __shared__ int cnt[NBUCKET];
    int t = threadIdx.x;
    int part = blockIdx.x & (NPART - 1);
    cnt[t] = 0;
    __syncthreads();
    int base = blockIdx.x * TILE + t;
    #pragma unroll
    for (int k = 0; k < VPT; ++k) {
        int e = base + k * BT;
        if (e < N_EDGES) atomicAdd(&cnt[src[e] / NPB], 1);
    }
    __syncthreads();
    int c = cnt[t];
    if (c) atomicAdd(&bucketCount[t * NPART + part], c);
}

// ---------- scan over 4096 (bucket,part) counters (1 block, 1024 thr) ----------
__global__ __launch_bounds__(1024) void bucket_scan(const int* __restrict__ bucketCount,
                                                    int* __restrict__ bucketOffset,
                                                    int* __restrict__ gCur,
                                                    int* __restrict__ rowPtr) {
    __shared__ int s[1024];
    int t = threadIdx.x;
    int4 c = *(const int4*)(bucketCount + t * 4);
    int sum = c.x + c.y + c.z + c.w;
    s[t] = sum;
    __syncthreads();
    for (int off = 1; off < 1024; off <<= 1) {
        int x = (t >= off) ? s[t - off] : 0;
        __syncthreads();
        s[t] += x;
        __syncthreads();
    }
    int base = s[t] - sum;   // exclusive
    int i0 = t * 4;
    bucketOffset[i0]     = base;
    bucketOffset[i0 + 1] = base + c.x;
    bucketOffset[i0 + 2] = base + c.x + c.y;
    bucketOffset[i0 + 3] = base + c.x + c.y + c.z;
    gCur[i0]     = base;
    gCur[i0 + 1] = base + c.x;
    gCur[i0 + 2] = base + c.x + c.y;
    gCur[i0 + 3] = base + c.x + c.y + c.z;
    if (t == 0) {
        bucketOffset[NCNT] = N_EDGES;
        rowPtr[N_NODES] = N_EDGES;
    }
}

// ---------- pass B: scatter packed edges into (bucket,part) runs ----------
// packed u64: [norm:32][src_local:9][dst:18]
__global__ __launch_bounds__(BT) void bucket_scatter(const int* __restrict__ src,
                                                     const int* __restrict__ dst,
                                                     const float* __restrict__ norm,
                                                     int* __restrict__ gCur,
                                                     u64* __restrict__ bpair) {
    __shared__ int cnt[NBUCKET];
    __shared__ int bbase[NBUCKET];
    int t = threadIdx.x;
    int part = blockIdx.x & (NPART - 1);
    cnt[t] = 0;
    __syncthreads();
    int base = blockIdx.x * TILE + t;
    #pragma unroll
    for (int k = 0; k < VPT; ++k) {
        int e = base + k * BT;
        if (e < N_EDGES) atomicAdd(&cnt[src[e] / NPB], 1);
    }
    __syncthreads();
    int c = cnt[t];
    bbase[t] = c ? atomicAdd(&gCur[t * NPART + part], c) : 0;
    __syncthreads();
    cnt[t] = 0;
    __syncthreads();
    #pragma unroll
    for (int k = 0; k < VPT; ++k) {
        int e = base + k * BT;
        if (e < N_EDGES) {
            int s = src[e];
            int b = s / NPB;
            int sl = s - b * NPB;                    // 0..292
            int r = atomicAdd(&cnt[b], 1);
            uint lo = (uint)dst[e] | ((uint)sl << 18);
            u64 packed = (u64)lo | ((u64)(uint)__float_as_uint(norm[e]) << 32);
            bpair[bbase[b] + r] = packed;
        }
    }
}

// ---------- pass C: per-bucket CSR finalize (counting sort by src_local) ----------
__global__ __launch_bounds__(1024) void csr_finalize(const int* __restrict__ bucketOffset,
                                                     const u64* __restrict__ bpair,
                                                     int* __restrict__ rowPtr,
                                                     u64* __restrict__ pairs) {
    __shared__ int cnt[NBUCKET];
    __shared__ int cur[NBUCKET];
    int b = blockIdx.x;
    int t = threadIdx.x;          // 1024 threads
    int beg = bucketOffset[b * NPART];
    int end = bucketOffset[b * NPART + NPART];
    int nodeBase = b * NPB;

    if (t < NBUCKET) cnt[t] = 0;
    __syncthreads();
    for (int i = beg + t; i < end; i += 1024) {
        uint lo = (uint)bpair[i];
        atomicAdd(&cnt[(lo >> 18) & 0x1FF], 1);
    }
    __syncthreads();
    int v = (t < NBUCKET) ? cnt[t] : 0;
    for (int off = 1; off < NBUCKET; off <<= 1) {     // inclusive scan, 512-wide
        int x = (t >= off && t < NBUCKET) ? cnt[t - off] : 0;
        __syncthreads();
        if (t < NBUCKET) cnt[t] += x;
        __syncthreads();
    }
    if (t < NBUCKET) {
        int excl = cnt[t] - v;
        cur[t] = excl;
        int node = nodeBase + t;
        if (t < NPB && node < N_NODES) rowPtr[node] = beg + excl;
    }
    __syncthreads();
    for (int i = beg + t; i < end; i += 1024) {
        u64 p = bpair[i];
        int s = ((uint)p >> 18) & 0x1FF;
        int r = atomicAdd(&cur[s], 1);
        pairs[beg + r] = p;
    }
}

// ---------- gather: 2 nodes/wave, 4 lane-groups of 8 per node ----------
// finalMode==0: nego = fp16(s)                    (no acc access)
// finalMode==1: acc  = (e0 + e1 + ego + s) * 0.25 (no nego write)
__global__ void lgcn_gather(const ushort* __restrict__ ego,
                            ushort* __restrict__ nego,
                            float* __restrict__ acc,
                            const ushort* __restrict__ e0,
                            const ushort* __restrict__ e1,
                            const int* __restrict__ rowPtr,
                            const u64* __restrict__ pairs,
                            int finalMode) {
    // 256 threads = 4 waves = 8 nodes (one node per 32-lane half-wave)
    int node   = blockIdx.x * 8 + (threadIdx.x >> 5);
    int lane32 = threadIdx.x & 31;
    int g      = lane32 >> 3;       // 4 edge streams per node
    int sub    = lane32 & 7;        // uint4 position within the 128B row
    if (node >= N_NODES) return;
    int beg = rowPtr[node];
    int end = rowPtr[node + 1];

    float s0 = 0.f, s1 = 0.f, s2 = 0.f, s3 = 0.f;
    float s4 = 0.f, s5 = 0.f, s6 = 0.f, s7 = 0.f;
    for (int i = beg + g; i < end; i += 4) {
        u64 p = pairs[i];                       // cached: re-read by layers 2/3
        uint lo = (uint)p;
        float w = __uint_as_float((uint)(p >> 32));
        int d = lo & 0x3FFFF;
        uint4 r = *(const uint4*)(ego + ((size_t)d << 6) + (sub << 3));
        float2 q;
        q = h2f2(r.x); s0 += w * q.x; s1 += w * q.y;
        q = h2f2(r.y); s2 += w * q.x; s3 += w * q.y;
        q = h2f2(r.z); s4 += w * q.x; s5 += w * q.y;
        q = h2f2(r.w); s6 += w * q.x; s7 += w * q.y;
    }

    // reduce 4 streams -> lanes (lane32 < 8) of each half-wave.
    // shuffles stay within the 32-lane group (offsets 16 and 8).
    s0 += __shfl_down(s0, 16); s1 += __shfl_down(s1, 16);
    s2 += __shfl_down(s2, 16); s3 += __shfl_down(s3, 16);
    s4 += __shfl_down(s4, 16); s5 += __shfl_down(s5, 16);
    s6 += __shfl_down(s6, 16); s7 += __shfl_down(s7, 16);
    s0 += __shfl_down(s0, 8);  s1 += __shfl_down(s1, 8);
    s2 += __shfl_down(s2, 8);  s3 += __shfl_down(s3, 8);
    s4 += __shfl_down(s4, 8);  s5 += __shfl_down(s5, 8);
    s6 += __shfl_down(s6, 8);  s7 += __shfl_down(s7, 8);

    if (lane32 < 8) {
        size_t ro = ((size_t)node << 6) + (lane32 << 3);   // dims lane32*8..+7
        if (!finalMode) {
            uint4* np = (uint4*)(nego + ro);
            *np = make_uint4(f2h2(s0, s1), f2h2(s2, s3),
                             f2h2(s4, s5), f2h2(s6, s7));
        } else {
            uint4 z0 = *(const uint4*)(e0  + ro);
            uint4 z1 = *(const uint4*)(e1  + ro);
            uint4 z2 = *(const uint4*)(ego + ro);
            float2 a, b, c;
            float4 o0, o1;
            a = h2f2(z0.x); b = h2f2(z1.x); c = h2f2(z2.x);
            o0.x = (a.x + b.x + c.x + s0) * 0.25f;
            o0.y = (a.y + b.y + c.y + s1) * 0.25f;
            a = h2f2(z0.y); b = h2f2(z1.y); c = h2f2(z2.y);
            o0.z = (a.x + b.x + c.x + s2) * 0.25f;
            o0.w = (a.y + b.y + c.y + s3) * 0.25f;
            a = h2f2(z0.z); b = h2f2(z1.z); c = h2f2(z2.z);
            o1.x = (a.x + b.x + c.x + s4) * 0.25f;
            o1.y = (a.y + b.y + c.y + s5) * 0.25f;
            a = h2f2(z0.w); b = h2f2(z1.w); c = h2f2(z2.w);
            o1.z = (a.x + b.x + c.x + s6) * 0.25f;
            o1.w = (a.y + b.y + c.y + s7) * 0.25f;
            float4* ap = (float4*)(acc + ro);
            ap[0] = o0;
            ap[1] = o1;
        }
    }
}

extern "C" void kernel_launch(void* const* d_in, const int* in_sizes, int n_in,
                              void* d_out, int out_size, void* d_ws, size_t ws_size,
                              hipStream_t stream) {
    const float* user_emb  = (const float*)d_in[0];
    const float* item_emb  = (const float*)d_in[1];
    const float* edge_norm = (const float*)d_in[2];
    const int*   edge_src  = (const int*)d_in[3];
    const int*   edge_dst  = (const int*)d_in[4];
    float* acc = (float*)d_out;

    char* w = (char*)d_ws;
    ushort* egoA  = (ushort*)w;                      w += (size_t)NODE_FLOATS * 2;   // 19.2 MB
    ushort* egoB  = (ushort*)w;                      w += (size_t)NODE_FLOATS * 2;   // 19.2 MB
    u64*   pairs  = (u64*)w;                         w += (size_t)N_EDGES * 8;       // 16 MB
    int*   rowPtr = (int*)w;                         w += (size_t)(N_NODES + 4) * 4;
    int*   bucketCount  = (int*)w;                   w += (size_t)NCNT * 4;
    int*   bucketOffset = (int*)w;                   w += (size_t)(NCNT + 4) * 4;
    int*   gCur   = (int*)w;                         w += (size_t)NCNT * 4;
    // bpair (16 MB, dead after csr_finalize) and egoC (19.2 MB, born at
    // layer-2 gather) share the tail region: lifetimes don't overlap.
    u64*   bpair  = (u64*)w;
    ushort* egoC  = (ushort*)w;

    const int T = 256;
    const int EW_BLOCKS = 2048;
    const int GATHER_BLOCKS = (N_NODES + 7) / 8;     // 18750

    lgcn_init<<<EW_BLOCKS, T, 0, stream>>>(
        (const float4*)user_emb, (const float4*)item_emb, (uint2*)egoA);

    zero_ints<<<NCNT / T, T, 0, stream>>>(bucketCount, NCNT);
    bucket_hist<<<NTILE, BT, 0, stream>>>(edge_src, bucketCount);
    bucket_scan<<<1, 1024, 0, stream>>>(bucketCount, bucketOffset, gCur, rowPtr);
    bucket_scatter<<<NTILE, BT, 0, stream>>>(edge_src, edge_dst, edge_norm,
                                             gCur, bpair);
    csr_finalize<<<NBUCKET, 1024, 0, stream>>>(bucketOffset, bpair,
                                               rowPtr, pairs);

    // Layer 1: ego0(A) -> ego1(B)             (nego only)
    lgcn_gather<<<GATHER_BLOCKS, T, 0, stream>>>(egoA, egoB, acc,
                                                 (const ushort*)0, (const ushort*)0,
                                                 rowPtr, pairs, 0);
    // Layer 2: ego1(B) -> ego2(C)             (nego only)
    lgcn_gather<<<GATHER_BLOCKS, T, 0, stream>>>(egoB, egoC, acc,
                                                 (const ushort*)0, (const ushort*)0,
                                                 rowPtr, pairs, 0);
    // Layer 3: ego2(C) -> s; acc = (A + B + C + s) / 4
    lgcn_gather<<<GATHER_BLOCKS, T, 0, stream>>>(egoC, (ushort*)0, acc,
                                                 egoA, egoB,
                                                 rowPtr, pairs, 1);
}